// Round 9
// baseline (389.922 us; speedup 1.0000x reference)
//
#include <hip/hip_runtime.h>
#include <math.h>

#define NB   8192
#define NTOK 21
#define NP   10

typedef _Float16 f16_t;
typedef _Float16 f16x8 __attribute__((ext_vector_type(8)));
typedef _Float16 f16x4 __attribute__((ext_vector_type(4)));
typedef float    f32x4 __attribute__((ext_vector_type(4)));

// swizzled element-index helpers (f16 units; XOR at 8-element = 16B granularity)
#define ROW128(r,c) ((r)*128 + ((c) ^ (((r)&7)<<3)))   // [.][128] tiles, 256B rows
#define VTIDX(d,m)  ((d)*32  + ((m) ^ (((d)&3)<<3)))   // vt [128][32], 64B rows
#define ATIDX(r,m)  ((r)*32  + ((m) ^ (((r)&3)<<3)))   // prob rows, 64B rows
#define TOK0(mt)    ((mt) ? 8 : 0)                     // overlapped row tiles {0-15},{8-23}

#define MFMA(a,b,c) __builtin_amdgcn_mfma_f32_16x16x32_f16((a),(b),(c),0,0,0)

// ---- kernel 1: blocks [0,384): weights -> f16 B-fragment layout [k>>3][n][8]
//      blocks [384,2944): per-patch-row norms of zc-rmsnorm(x) -> 64 atomic slots
__global__ __launch_bounds__(256) void k_prep(
    const float* __restrict__ Wqkv, const float* __restrict__ Wout,
    const float* __restrict__ Wg,   const float* __restrict__ Wr,
    const float* __restrict__ x,    const float* __restrict__ g,
    f16_t* __restrict__ wq, f16_t* __restrict__ wo,
    f16_t* __restrict__ wgb, f16_t* __restrict__ wrb,
    float* __restrict__ part)
{
    __shared__ float sd[4];
    if (blockIdx.x < 384) {
        int i = blockIdx.x * 256 + threadIdx.x;       // 0 .. 98303
        if (i < 49152) {
            int k = i / 384, n = i - k * 384;
            wq[((k >> 3) * 384 + n) * 8 + (k & 7)] = (f16_t)Wqkv[i];
        } else {
            int j = i - 49152;
            int sel = j >> 14;                        // 0=Wout 1=Wg 2=Wr
            int t = j & 16383;
            int k = t >> 7, n = t & 127;
            const float* src = sel == 0 ? Wout : (sel == 1 ? Wg : Wr);
            f16_t* dst = sel == 0 ? wo : (sel == 1 ? wgb : wrb);
            dst[((k >> 3) * 128 + n) * 8 + (k & 7)] = (f16_t)src[t];
        }
    } else {
        const int nb = blockIdx.x - 384;              // 0 .. 2559, 32 rows each
        const int wave = threadIdx.x >> 6, lane = threadIdx.x & 63;
        const float g0v = g[lane], g1v = g[lane + 64];
        float acc = 0.f;
        #pragma unroll
        for (int rr = 0; rr < 8; rr++) {
            int row = nb * 32 + wave * 8 + rr;        // 0 .. 81919
            int b = row / NP, p = row - b * NP;
            const float* xr = x + (size_t)b * 2688 + (2 * p + 1) * 128;
            float a0 = xr[lane], a1 = xr[lane + 64];
            float s = a0 + a1, sq = a0 * a0 + a1 * a1;
            #pragma unroll
            for (int off = 32; off; off >>= 1) { s += __shfl_xor(s, off); sq += __shfl_xor(sq, off); }
            float mean = s * (1.0f / 128);
            float rstd = rsqrtf(sq * (1.0f / 128) - mean * mean + 1e-8f);
            float h0 = (a0 - mean) * rstd * g0v;
            float h1 = (a1 - mean) * rstd * g1v;
            float n2 = h0 * h0 + h1 * h1;
            #pragma unroll
            for (int off = 32; off; off >>= 1) n2 += __shfl_xor(n2, off);
            if (lane == 0) acc += sqrtf(n2);
        }
        if (lane == 0) sd[wave] = acc;
        __syncthreads();
        if (threadIdx.x == 0)
            atomicAdd(&part[(nb & 63) * 16], sd[0] + sd[1] + sd[2] + sd[3]);
    }
}

// ---------------- kernel 2: fused per-batch pipeline, f16 MFMA, 5 blocks/CU ----------------
__global__ __launch_bounds__(256, 5) void k_main(
    const float* __restrict__ x,   const float* __restrict__ fcr,
    const float* __restrict__ fci, const float* __restrict__ g,
    const float* __restrict__ bqkv, const float* __restrict__ bout,
    const float* __restrict__ bg,   const float* __restrict__ br,
    const float* __restrict__ Bb,   const float* __restrict__ part,
    const f16_t* __restrict__ wq,  const f16_t* __restrict__ wo,
    const f16_t* __restrict__ wgb, const f16_t* __restrict__ wrb,
    float* __restrict__ out)
{
    __shared__ __align__(16) f16_t hsb[24 * 128];      // normed f16, swz; rows 21-23 = 0 (6K)
    __shared__ __align__(16) f16_t reg1[24 * 128];     // qb -> y2bb[10][128] (6K)
    __shared__ __align__(16) f16_t reg2[24 * 128];     // kb -> yb (6K)
    __shared__ __align__(16) f16_t reg3[128 * 32];     // vt[d][m] (zeroed) -> gyb f32[10][128] (8K)
    __shared__ __align__(16) char  pool[5376];         // fcs+fis (P2) | attb[2][24][32]+att2e[2][16][32]
    __shared__ float normv[11];                        // [0..9] patch norms, [10] global mean
    // total ~32.0 KB -> 5 blocks/CU

    float* fcs  = (float*)pool;            // [21*32] f32 (P2 only)
    float* fis  = (float*)pool + 672;      // [21*32] f32 (P2 only)

    const int tid = threadIdx.x;
    const int w = tid >> 6, l = tid & 63, l15 = l & 15, gq = l >> 4;
    const int b = blockIdx.x;
    const float* xb = x + (size_t)b * 2688;

    // ---- P1: stage rope tables; zero pads+vt; zc-rmsnorm -> hsb (16-lane groups); mean ----
    {
        const float4* c4 = (const float4*)fcr; float4* dc = (float4*)fcs;
        const float4* i4 = (const float4*)fci; float4* di = (float4*)fis;
        if (tid < 168) { dc[tid] = c4[tid]; di[tid] = i4[tid]; }
        f16x8 zz;
        #pragma unroll
        for (int j = 0; j < 8; j++) zz[j] = (f16_t)0.f;
        {   // zero vt (reg3): 512 chunks of 8
            f16x8* z = (f16x8*)reg3;
            z[tid] = zz; z[tid + 256] = zz;
        }
        if (tid < 48) {  // zero hsb rows 21..23
            int r = 21 + (tid >> 4), c0 = (tid & 15) * 8;
            *(f16x8*)&hsb[ROW128(r, c0)] = zz;
        }
        if (tid < 64) {  // global norm mean
            float s = part[tid * 16];
            #pragma unroll
            for (int off = 32; off; off >>= 1) s += __shfl_xor(s, off);
            if (tid == 0) normv[10] = s * (1.f / 81920.f);
        }
        // zc-rmsnorm: one 16-lane group per row, 8 elems/lane
        const int gid = tid >> 4, lane16 = tid & 15;
        const int c0 = lane16 * 8;
        float4 ga = *(const float4*)&g[c0];
        float4 gb4 = *(const float4*)&g[c0 + 4];
        for (int r = gid; r < 21; r += 16) {
            float4 a4 = *(const float4*)&xb[r * 128 + c0];
            float4 b4 = *(const float4*)&xb[r * 128 + c0 + 4];
            float s  = a4.x + a4.y + a4.z + a4.w + b4.x + b4.y + b4.z + b4.w;
            float sq = a4.x*a4.x + a4.y*a4.y + a4.z*a4.z + a4.w*a4.w
                     + b4.x*b4.x + b4.y*b4.y + b4.z*b4.z + b4.w*b4.w;
            #pragma unroll
            for (int off = 8; off; off >>= 1) { s += __shfl_xor(s, off); sq += __shfl_xor(sq, off); }
            float mean = s * (1.0f / 128);
            float rstd = rsqrtf(sq * (1.0f / 128) - mean * mean + 1e-8f);
            float h[8];
            h[0]=(a4.x-mean)*rstd*ga.x;  h[1]=(a4.y-mean)*rstd*ga.y;
            h[2]=(a4.z-mean)*rstd*ga.z;  h[3]=(a4.w-mean)*rstd*ga.w;
            h[4]=(b4.x-mean)*rstd*gb4.x; h[5]=(b4.y-mean)*rstd*gb4.y;
            h[6]=(b4.z-mean)*rstd*gb4.z; h[7]=(b4.w-mean)*rstd*gb4.w;
            f16x8 hv;
            #pragma unroll
            for (int j = 0; j < 8; j++) hv[j] = (f16_t)h[j];
            *(f16x8*)&hsb[ROW128(r, c0)] = hv;
            if (r & 1) {
                float n2 = 0.f;
                #pragma unroll
                for (int j = 0; j < 8; j++) n2 += h[j] * h[j];
                #pragma unroll
                for (int off = 8; off; off >>= 1) n2 += __shfl_xor(n2, off);
                if (lane16 == 0) normv[r >> 1] = sqrtf(n2);
            }
        }
    }
    __syncthreads();

    // ---- P2: qkv = h @ Wqkv + b (MFMA); rope q/k in-reg; scatter q->reg1 k->reg2 v->vt ----
    {
        f16x8 afr[2][4];
        #pragma unroll
        for (int mt = 0; mt < 2; mt++)
            #pragma unroll
            for (int ks = 0; ks < 4; ks++)
                afr[mt][ks] = *(const f16x8*)&hsb[ROW128(TOK0(mt) + l15, ks * 32 + gq * 8)];
        #pragma unroll 2
        for (int q6 = 0; q6 < 6; ++q6) {
            int nt = w * 6 + q6;
            int n = nt * 16 + l15;
            f16x8 bfr[4];
            #pragma unroll
            for (int ks = 0; ks < 4; ks++)
                bfr[ks] = *(const f16x8*)&wq[((ks * 4 + gq) * 384 + n) * 8];
            float bias = bqkv[n];
            #pragma unroll
            for (int mt = 0; mt < 2; mt++) {
                f32x4 acc = {0.f, 0.f, 0.f, 0.f};
                #pragma unroll
                for (int ks = 0; ks < 4; ks++) acc = MFMA(afr[mt][ks], bfr[ks], acc);
                int rbase = TOK0(mt) + gq * 4;
                if (n < 256) {                       // q or k: rope then store f16
                    int d = n & 63, j = d >> 1;
                    bool ev = !(d & 1);
                    f16_t* dst = (n < 128) ? reg1 : reg2;
                    int cc = n & 127;
                    #pragma unroll
                    for (int i = 0; i < 4; i++) {
                        int r = rbase + i; int rr = r < 21 ? r : 0;
                        float v = acc[i] + bias;
                        float p = __shfl_xor(v, 1);  // partner holds the pair's other half
                        float fr = fcs[rr * 32 + j], fi = fis[rr * 32 + j];
                        float o = ev ? (v * fr - p * fi) : (p * fi + v * fr);
                        dst[ROW128(r, cc)] = (f16_t)o;
                    }
                } else {                             // v: store transposed vt[d][m]
                    int d = n - 256;
                    f16x4 pv;
                    #pragma unroll
                    for (int i = 0; i < 4; i++) pv[i] = (f16_t)(acc[i] + bias);
                    *(f16x4*)&reg3[VTIDX(d, rbase)] = pv;   // rbase 4-aligned, no 8-cross
                }
            }
        }
    }
    __syncthreads();

    // ---- P3': scores + in-register softmax -> f16 prob fragments in pool ----
    {
        f16_t* attb  = (f16_t*)pool;           // [2][24][32]
        f16_t* att2e = (f16_t*)pool + 1536;    // [2][16][32]
        // full attention: wave w -> head hh = w>>1, row-tile mt = w&1
        {
            const int hh = w >> 1, mt = w & 1;
            const int b1row = (16 + l15 < 21) ? 16 + l15 : 20;
            f32x4 acc0 = {0.f, 0.f, 0.f, 0.f}, acc1 = {0.f, 0.f, 0.f, 0.f};
            #pragma unroll
            for (int ks = 0; ks < 2; ks++) {
                f16x8 a  = *(const f16x8*)&reg1[ROW128(TOK0(mt) + l15, hh * 64 + ks * 32 + gq * 8)];
                f16x8 b0 = *(const f16x8*)&reg2[ROW128(l15,            hh * 64 + ks * 32 + gq * 8)];
                f16x8 b1 = *(const f16x8*)&reg2[ROW128(b1row,          hh * 64 + ks * 32 + gq * 8)];
                acc0 = MFMA(a, b0, acc0);
                acc1 = MFMA(a, b1, acc1);
            }
            const int m0 = l15, m1 = 16 + l15;
            const bool c1 = (m1 < 21);
            #pragma unroll
            for (int i = 0; i < 4; i++) {
                int r = TOK0(mt) + gq * 4 + i;
                int rr = r < 21 ? r : 0;
                float v0 = acc0[i] * 0.125f + Bb[rr * 21 + m0];
                float v1 = c1 ? acc1[i] * 0.125f + Bb[rr * 21 + m1] : -1e30f;
                float mx = fmaxf(v0, v1);
                #pragma unroll
                for (int off = 8; off; off >>= 1) mx = fmaxf(mx, __shfl_xor(mx, off));
                float e0 = __expf(v0 - mx);
                float e1 = c1 ? __expf(v1 - mx) : 0.f;
                float s = e0 + e1;
                #pragma unroll
                for (int off = 8; off; off >>= 1) s += __shfl_xor(s, off);
                float is = 1.f / s;
                bool rv = (r < 21);
                attb[hh * 768 + ATIDX(r, m0)] = (f16_t)(rv ? e0 * is : 0.f);
                attb[hh * 768 + ATIDX(r, m1)] = (f16_t)(rv ? e1 * is : 0.f);
            }
        }
        // patch/stat attention: waves 0,2 -> head w>>1
        if ((w & 1) == 0) {
            const int hh = w >> 1;
            int ra = 2 * l15 + 1; if (ra > 20) ra = 20;
            int rb = 2 * l15;     if (rb > 20) rb = 20;
            f32x4 acc = {0.f, 0.f, 0.f, 0.f};
            #pragma unroll
            for (int ks = 0; ks < 2; ks++) {
                f16x8 a  = *(const f16x8*)&reg1[ROW128(ra, hh * 64 + ks * 32 + gq * 8)];
                f16x8 bb = *(const f16x8*)&reg2[ROW128(rb, hh * 64 + ks * 32 + gq * 8)];
                acc = MFMA(a, bb, acc);
            }
            const bool cv = (l15 < 11);
            #pragma unroll
            for (int i = 0; i < 4; i++) {
                int p = gq * 4 + i;
                float v = cv ? acc[i] * 0.125f : -1e30f;
                float mx = v;
                #pragma unroll
                for (int off = 8; off; off >>= 1) mx = fmaxf(mx, __shfl_xor(mx, off));
                float e = cv ? __expf(v - mx) : 0.f;
                float s = e;
                #pragma unroll
                for (int off = 8; off; off >>= 1) s += __shfl_xor(s, off);
                float is = 1.f / s;
                att2e[hh * 512 + ATIDX(p, 2 * l15)]     = (f16_t)((p < 10) ? e * is : 0.f);
                att2e[hh * 512 + ATIDX(p, 2 * l15 + 1)] = (f16_t)0.f;
            }
        }
    }
    __syncthreads();

    // ---- P6: y = attb @ v (into reg2); y2 = att2e @ v (into y2bb = reg1, q dead) ----
    {
        f16_t* attb  = (f16_t*)pool;
        f16_t* att2e = (f16_t*)pool + 1536;
        f16_t* y2bb  = reg1;                          // [10][128] f16 swz
        for (int t = w * 6; t < w * 6 + 6; ++t) {     // 24 tiles: 16 y + 8 y2
            int hh, dloc, mt = 0, isY2;
            if (t < 16) { hh = t >> 3; mt = (t >> 2) & 1; dloc = hh * 64 + (t & 3) * 16 + l15; isY2 = 0; }
            else        { int u = t - 16; hh = u >> 2;    dloc = hh * 64 + (u & 3) * 16 + l15; isY2 = 1; }
            f16x8 a;
            if (!isY2) { int r = TOK0(mt) + l15; a = *(const f16x8*)&attb[hh * 768 + ATIDX(r, gq * 8)]; }
            else       {                         a = *(const f16x8*)&att2e[hh * 512 + ATIDX(l15, gq * 8)]; }
            f16x8 bb = *(const f16x8*)&reg3[VTIDX(dloc, gq * 8)];
            f32x4 acc = {0.f, 0.f, 0.f, 0.f};
            acc = MFMA(a, bb, acc);
            if (!isY2) {
                #pragma unroll
                for (int i = 0; i < 4; i++) reg2[ROW128(TOK0(mt) + gq * 4 + i, dloc)] = (f16_t)acc[i];
            } else {
                #pragma unroll
                for (int i = 0; i < 4; i++) {
                    int rr2 = gq * 4 + i;
                    if (rr2 < 10) y2bb[ROW128(rr2, dloc)] = (f16_t)acc[i];
                }
            }
        }
    }
    __syncthreads();

    // ---- P7a: gate & refine GEMMs; gy -> gyb (vt region, now dead) ----
    {
        f16_t* y2bb = reg1;
        float mn = normv[10];
        float* gyb = (float*)reg3;                    // [10][128] f32
        #pragma unroll
        for (int q2 = 0; q2 < 2; q2++) {
            int nt = w * 2 + q2;
            int n = nt * 16 + l15;
            int yrow = l15 < 10 ? l15 : 0;
            int hr   = l15 < 10 ? 2 * l15 + 1 : 1;
            f32x4 accg = {0.f, 0.f, 0.f, 0.f}, accr = {0.f, 0.f, 0.f, 0.f};
            #pragma unroll
            for (int ks = 0; ks < 4; ks++) {
                f16x8 wgf = *(const f16x8*)&wgb[((ks * 4 + gq) * 128 + n) * 8];
                f16x8 wrf = *(const f16x8*)&wrb[((ks * 4 + gq) * 128 + n) * 8];
                f16x8 ha  = *(const f16x8*)&hsb[ROW128(hr, ks * 32 + gq * 8)];
                f16x8 ya  = *(const f16x8*)&y2bb[ROW128(yrow, ks * 32 + gq * 8)];
                accg = MFMA(ha, wgf, accg);
                accr = MFMA(ya, wrf, accr);
            }
            float bgc = bg[n], brc = br[n];
            #pragma unroll
            for (int i = 0; i < 4; i++) {
                int p = gq * 4 + i;
                if (p < 10) {
                    float gate = 1.f / (1.f + __expf(-(accg[i] + bgc)));
                    float u = 1.f - 1.f / (1.f + __expf(-(normv[p] - mn)));
                    gyb[p * 128 + n] = u * gate * (accr[i] + brc);
                }
            }
        }
    }
    __syncthreads();

    // ---- P7b: out = x + y @ Wout + bout (+ gy on patch rows); x re-read from global ----
    {
        float* gyb = (float*)reg3;
        float* ob = out + (size_t)b * 2688;
        for (int t = w * 4; t < w * 4 + 4; ++t) {     // 16 tiles
            int mt = t >> 3, nt = t & 7;
            int n = nt * 16 + l15;
            f32x4 acc = {0.f, 0.f, 0.f, 0.f};
            #pragma unroll
            for (int ks = 0; ks < 4; ks++) {
                f16x8 a  = *(const f16x8*)&reg2[ROW128(TOK0(mt) + l15, ks * 32 + gq * 8)];
                f16x8 wf = *(const f16x8*)&wo[((ks * 4 + gq) * 128 + n) * 8];
                acc = MFMA(a, wf, acc);
            }
            float bo = bout[n];
            #pragma unroll
            for (int i = 0; i < 4; i++) {
                int r = TOK0(mt) + gq * 4 + i;
                if (r < 21) {
                    float v = xb[r * 128 + n] + acc[i] + bo;
                    if (r & 1) v += gyb[((r - 1) >> 1) * 128 + n];
                    ob[r * 128 + n] = v;
                }
            }
        }
    }
}

extern "C" void kernel_launch(void* const* d_in, const int* in_sizes, int n_in,
                              void* d_out, int out_size, void* d_ws, size_t ws_size,
                              hipStream_t stream)
{
    (void)in_sizes; (void)n_in; (void)out_size; (void)ws_size;
    const float* x    = (const float*)d_in[0];
    const float* fcr  = (const float*)d_in[1];
    const float* fci  = (const float*)d_in[2];
    const float* g    = (const float*)d_in[3];
    const float* Wqkv = (const float*)d_in[4];
    const float* bqkv = (const float*)d_in[5];
    const float* Wout = (const float*)d_in[6];
    const float* bout = (const float*)d_in[7];
    const float* Wg   = (const float*)d_in[8];
    const float* bg   = (const float*)d_in[9];
    const float* Wr   = (const float*)d_in[10];
    const float* br   = (const float*)d_in[11];
    const float* Bb   = (const float*)d_in[12];
    float* out = (float*)d_out;

    char* wsb = (char*)d_ws;
    float* part = (float*)wsb;                          // 64 slots x 16-float stride (4KB)
    f16_t* wq  = (f16_t*)(wsb + 4096);                  // 49152 f16
    f16_t* wo  = wq + 49152;                            // 16384
    f16_t* wgb = wo + 16384;                            // 16384
    f16_t* wrb = wgb + 16384;                           // 16384 ; ws use ~200 KB

    hipMemsetAsync(part, 0, 4096, stream);
    hipLaunchKernelGGL(k_prep, dim3(2944), dim3(256), 0, stream,
                       Wqkv, Wout, Wg, Wr, x, g, wq, wo, wgb, wrb, part);
    hipLaunchKernelGGL(k_main, dim3(NB),   dim3(256), 0, stream,
                       x, fcr, fci, g, bqkv, bout, bg, br, Bb, part, wq, wo, wgb, wrb, out);
}

// Round 13
// 336.653 us; speedup vs baseline: 1.1582x; 1.1582x over previous
//
#include <hip/hip_runtime.h>
#include <math.h>

#define NB   8192
#define NTOK 21
#define NP   10

typedef _Float16 f16_t;
typedef _Float16 f16x8 __attribute__((ext_vector_type(8)));
typedef _Float16 f16x4 __attribute__((ext_vector_type(4)));
typedef float    f32x4 __attribute__((ext_vector_type(4)));

// swizzled element-index helpers (f16 units; XOR at 8-element = 16B granularity)
#define ROW128(r,c) ((r)*128 + ((c) ^ (((r)&7)<<3)))   // [.][128] tiles, 256B rows
#define VTIDX(d,m)  ((d)*32  + ((m) ^ (((d)&3)<<3)))   // vt [128][32], 64B rows
#define ATIDX(r,m)  ((r)*32  + ((m) ^ (((r)&3)<<3)))   // prob rows, 64B rows

#define MFMA(a,b,c) __builtin_amdgcn_mfma_f32_16x16x32_f16((a),(b),(c),0,0,0)

// ---- kernel 1: blocks [0,384): weights -> f16 B-fragment layout [k>>3][n][8]
//      blocks [384,2944): per-patch-row norms of zc-rmsnorm(x) -> 64 atomic slots
__global__ __launch_bounds__(256) void k_prep(
    const float* __restrict__ Wqkv, const float* __restrict__ Wout,
    const float* __restrict__ Wg,   const float* __restrict__ Wr,
    const float* __restrict__ x,    const float* __restrict__ g,
    f16_t* __restrict__ wq, f16_t* __restrict__ wo,
    f16_t* __restrict__ wgb, f16_t* __restrict__ wrb,
    float* __restrict__ part)
{
    __shared__ float sd[4];
    if (blockIdx.x < 384) {
        int i = blockIdx.x * 256 + threadIdx.x;       // 0 .. 98303
        if (i < 49152) {
            int k = i / 384, n = i - k * 384;
            wq[((k >> 3) * 384 + n) * 8 + (k & 7)] = (f16_t)Wqkv[i];
        } else {
            int j = i - 49152;
            int sel = j >> 14;                        // 0=Wout 1=Wg 2=Wr
            int t = j & 16383;
            int k = t >> 7, n = t & 127;
            const float* src = sel == 0 ? Wout : (sel == 1 ? Wg : Wr);
            f16_t* dst = sel == 0 ? wo : (sel == 1 ? wgb : wrb);
            dst[((k >> 3) * 128 + n) * 8 + (k & 7)] = (f16_t)src[t];
        }
    } else {
        const int nb = blockIdx.x - 384;              // 0 .. 2559, 32 rows each
        const int wave = threadIdx.x >> 6, lane = threadIdx.x & 63;
        const float g0v = g[lane], g1v = g[lane + 64];
        float acc = 0.f;
        #pragma unroll
        for (int rr = 0; rr < 8; rr++) {
            int row = nb * 32 + wave * 8 + rr;        // 0 .. 81919
            int b = row / NP, p = row - b * NP;
            const float* xr = x + (size_t)b * 2688 + (2 * p + 1) * 128;
            float a0 = xr[lane], a1 = xr[lane + 64];
            float s = a0 + a1, sq = a0 * a0 + a1 * a1;
            #pragma unroll
            for (int off = 32; off; off >>= 1) { s += __shfl_xor(s, off); sq += __shfl_xor(sq, off); }
            float mean = s * (1.0f / 128);
            float rstd = rsqrtf(sq * (1.0f / 128) - mean * mean + 1e-8f);
            float h0 = (a0 - mean) * rstd * g0v;
            float h1 = (a1 - mean) * rstd * g1v;
            float n2 = h0 * h0 + h1 * h1;
            #pragma unroll
            for (int off = 32; off; off >>= 1) n2 += __shfl_xor(n2, off);
            if (lane == 0) acc += sqrtf(n2);
        }
        if (lane == 0) sd[wave] = acc;
        __syncthreads();
        if (threadIdx.x == 0)
            atomicAdd(&part[(nb & 63) * 16], sd[0] + sd[1] + sd[2] + sd[3]);
    }
}

// -------- kernel 2: fused per-batch pipeline, f16 MFMA, reg-prefetch across barriers --------
__global__ __launch_bounds__(256, 4) void k_main(
    const float* __restrict__ x,   const float* __restrict__ fcr,
    const float* __restrict__ fci, const float* __restrict__ g,
    const float* __restrict__ bqkv, const float* __restrict__ bout,
    const float* __restrict__ bg,   const float* __restrict__ br,
    const float* __restrict__ Bb,   const float* __restrict__ part,
    const f16_t* __restrict__ wq,  const f16_t* __restrict__ wo,
    const f16_t* __restrict__ wgb, const f16_t* __restrict__ wrb,
    float* __restrict__ out)
{
    __shared__ __align__(16) f16_t hsb[32 * 128];      // normed f16, swz; rows 21-31 = 0 (8K)
    __shared__ __align__(16) f16_t reg1[32 * 128];     // qb -> y2bb[10][128] (8K)
    __shared__ __align__(16) f16_t reg2[32 * 128];     // kb -> yb (8K)
    __shared__ __align__(16) f16_t reg3[128 * 32];     // vt[d][m] (zeroed) -> gyb f32[10][128] (8K)
    __shared__ __align__(16) char  pool[6144];         // fcs+fis (P2) | attb[2][32][32]+att2e[2][16][32]
    __shared__ float normv[11];                        // [0..9] patch norms, [10] global mean
    // total ~38.2 KB -> 4 blocks/CU

    float* fcs  = (float*)pool;            // [21*32] f32 (P2 only)
    float* fis  = (float*)pool + 672;      // [21*32] f32 (P2 only)

    const int tid = threadIdx.x;
    const int w = tid >> 6, l = tid & 63, l15 = l & 15, gq = l >> 4;
    const int b = blockIdx.x;
    const float* xb = x + (size_t)b * 2688;

    // ---- top-of-kernel prefetch: P2 first weight tile + Bb rows for P3' ----
    f16x8 bfr[4];
    {
        int n0p = (w * 6) * 16 + l15;
        #pragma unroll
        for (int ks = 0; ks < 4; ks++)
            bfr[ks] = *(const f16x8*)&wq[((ks * 4 + gq) * 384 + n0p) * 8];
    }
    float bbv[8];
    {
        int mt = w & 1;
        int m0 = l15, m1 = (16 + l15 < 21) ? 16 + l15 : 20;
        #pragma unroll
        for (int i = 0; i < 4; i++) {
            int rr = mt * 16 + gq * 4 + i; rr = rr < 21 ? rr : 20;
            bbv[i]     = Bb[rr * 21 + m0];
            bbv[4 + i] = Bb[rr * 21 + m1];
        }
    }

    // ---- P1: stage rope tables; zero pads+vt; zc-rmsnorm -> hsb (16-lane groups); mean ----
    {
        const float4* c4 = (const float4*)fcr; float4* dc = (float4*)fcs;
        const float4* i4 = (const float4*)fci; float4* di = (float4*)fis;
        if (tid < 168) { dc[tid] = c4[tid]; di[tid] = i4[tid]; }
        f16x8 zz;
        #pragma unroll
        for (int j = 0; j < 8; j++) zz[j] = (f16_t)0.f;
        {   // zero vt (reg3): 512 chunks of 8
            f16x8* z = (f16x8*)reg3;
            z[tid] = zz; z[tid + 256] = zz;
        }
        if (tid < 176) {  // zero hsb rows 21..31 (11 rows x 16 chunks)
            int r = 21 + (tid >> 4), c0 = (tid & 15) * 8;
            *(f16x8*)&hsb[ROW128(r, c0)] = zz;
        }
        if (tid < 64) {  // global norm mean
            float s = part[tid * 16];
            #pragma unroll
            for (int off = 32; off; off >>= 1) s += __shfl_xor(s, off);
            if (tid == 0) normv[10] = s * (1.f / 81920.f);
        }
        // zc-rmsnorm: one 16-lane group per row, 8 elems/lane
        const int gid = tid >> 4, lane16 = tid & 15;
        const int c0 = lane16 * 8;
        float4 ga = *(const float4*)&g[c0];
        float4 gb4 = *(const float4*)&g[c0 + 4];
        for (int r = gid; r < 21; r += 16) {
            float4 a4 = *(const float4*)&xb[r * 128 + c0];
            float4 b4 = *(const float4*)&xb[r * 128 + c0 + 4];
            float s  = a4.x + a4.y + a4.z + a4.w + b4.x + b4.y + b4.z + b4.w;
            float sq = a4.x*a4.x + a4.y*a4.y + a4.z*a4.z + a4.w*a4.w
                     + b4.x*b4.x + b4.y*b4.y + b4.z*b4.z + b4.w*b4.w;
            #pragma unroll
            for (int off = 8; off; off >>= 1) { s += __shfl_xor(s, off); sq += __shfl_xor(sq, off); }
            float mean = s * (1.0f / 128);
            float rstd = rsqrtf(sq * (1.0f / 128) - mean * mean + 1e-8f);
            float h[8];
            h[0]=(a4.x-mean)*rstd*ga.x;  h[1]=(a4.y-mean)*rstd*ga.y;
            h[2]=(a4.z-mean)*rstd*ga.z;  h[3]=(a4.w-mean)*rstd*ga.w;
            h[4]=(b4.x-mean)*rstd*gb4.x; h[5]=(b4.y-mean)*rstd*gb4.y;
            h[6]=(b4.z-mean)*rstd*gb4.z; h[7]=(b4.w-mean)*rstd*gb4.w;
            f16x8 hv;
            #pragma unroll
            for (int j = 0; j < 8; j++) hv[j] = (f16_t)h[j];
            *(f16x8*)&hsb[ROW128(r, c0)] = hv;
            if (r & 1) {
                float n2 = 0.f;
                #pragma unroll
                for (int j = 0; j < 8; j++) n2 += h[j] * h[j];
                #pragma unroll
                for (int off = 8; off; off >>= 1) n2 += __shfl_xor(n2, off);
                if (lane16 == 0) normv[r >> 1] = sqrtf(n2);
            }
        }
    }
    __syncthreads();

    // ---- P2: qkv = h @ Wqkv + b (MFMA, 1-deep weight pipeline); rope; scatter q/k/v ----
    {
        f16x8 afr[2][4];
        #pragma unroll
        for (int mt = 0; mt < 2; mt++)
            #pragma unroll
            for (int ks = 0; ks < 4; ks++)
                afr[mt][ks] = *(const f16x8*)&hsb[ROW128(mt * 16 + l15, ks * 32 + gq * 8)];
        #pragma unroll
        for (int q6 = 0; q6 < 6; ++q6) {
            int nt = w * 6 + q6;
            int n = nt * 16 + l15;
            f16x8 bnext[4];
            if (q6 < 5) {
                #pragma unroll
                for (int ks = 0; ks < 4; ks++)
                    bnext[ks] = *(const f16x8*)&wq[((ks * 4 + gq) * 384 + (n + 16)) * 8];
            } else {
                #pragma unroll
                for (int ks = 0; ks < 4; ks++) bnext[ks] = bfr[ks];
            }
            float bias = bqkv[n];
            #pragma unroll
            for (int mt = 0; mt < 2; mt++) {
                f32x4 acc = {0.f, 0.f, 0.f, 0.f};
                #pragma unroll
                for (int ks = 0; ks < 4; ks++) acc = MFMA(afr[mt][ks], bfr[ks], acc);
                int rbase = mt * 16 + gq * 4;
                if (n < 256) {                       // q or k: rope then store f16
                    int d = n & 63, j = d >> 1;
                    bool ev = !(d & 1);
                    f16_t* dst = (n < 128) ? reg1 : reg2;
                    int cc = n & 127;
                    #pragma unroll
                    for (int i = 0; i < 4; i++) {
                        int r = rbase + i; int rr = r < 21 ? r : 0;
                        float v = acc[i] + bias;
                        float p = __shfl_xor(v, 1);  // partner holds the pair's other half
                        float fr = fcs[rr * 32 + j], fi = fis[rr * 32 + j];
                        float o = ev ? (v * fr - p * fi) : (p * fi + v * fr);
                        dst[ROW128(r, cc)] = (f16_t)o;
                    }
                } else {                             // v: store transposed vt[d][m]
                    int d = n - 256;
                    f16x4 pv;
                    #pragma unroll
                    for (int i = 0; i < 4; i++) pv[i] = (f16_t)(acc[i] + bias);
                    *(f16x4*)&reg3[VTIDX(d, rbase)] = pv;   // rbase 4-aligned, no 8-cross
                }
            }
            #pragma unroll
            for (int ks = 0; ks < 4; ks++) bfr[ks] = bnext[ks];
        }
    }
    __syncthreads();

    // ---- P3': scores + in-register softmax -> f16 prob fragments in pool ----
    {
        f16_t* attb  = (f16_t*)pool;           // [2][32][32]
        f16_t* att2e = (f16_t*)pool + 2048;    // [2][16][32]
        // full attention: wave w -> head hh = w>>1, row-tile mt = w&1
        {
            const int hh = w >> 1, mt = w & 1;
            const int b1row = (16 + l15 < 21) ? 16 + l15 : 20;
            f32x4 acc0 = {0.f, 0.f, 0.f, 0.f}, acc1 = {0.f, 0.f, 0.f, 0.f};
            #pragma unroll
            for (int ks = 0; ks < 2; ks++) {
                f16x8 a  = *(const f16x8*)&reg1[ROW128(mt * 16 + l15, hh * 64 + ks * 32 + gq * 8)];
                f16x8 b0 = *(const f16x8*)&reg2[ROW128(l15,           hh * 64 + ks * 32 + gq * 8)];
                f16x8 b1 = *(const f16x8*)&reg2[ROW128(b1row,         hh * 64 + ks * 32 + gq * 8)];
                acc0 = MFMA(a, b0, acc0);
                acc1 = MFMA(a, b1, acc1);
            }
            const int m0 = l15, m1 = 16 + l15;
            const bool c1 = (m1 < 21);
            #pragma unroll
            for (int i = 0; i < 4; i++) {
                int r = mt * 16 + gq * 4 + i;
                float v0 = acc0[i] * 0.125f + bbv[i];
                float v1 = c1 ? acc1[i] * 0.125f + bbv[4 + i] : -1e30f;
                float mx = fmaxf(v0, v1);
                #pragma unroll
                for (int off = 8; off; off >>= 1) mx = fmaxf(mx, __shfl_xor(mx, off));
                float e0 = __expf(v0 - mx);
                float e1 = c1 ? __expf(v1 - mx) : 0.f;
                float s = e0 + e1;
                #pragma unroll
                for (int off = 8; off; off >>= 1) s += __shfl_xor(s, off);
                float is = 1.f / s;
                bool rv = (r < 21);
                attb[hh * 1024 + ATIDX(r, m0)] = (f16_t)(rv ? e0 * is : 0.f);
                attb[hh * 1024 + ATIDX(r, m1)] = (f16_t)(rv ? e1 * is : 0.f);
            }
        }
        // patch/stat attention: waves 0,2 -> head w>>1
        if ((w & 1) == 0) {
            const int hh = w >> 1;
            int ra = 2 * l15 + 1; if (ra > 20) ra = 20;
            int rb = 2 * l15;     if (rb > 20) rb = 20;
            f32x4 acc = {0.f, 0.f, 0.f, 0.f};
            #pragma unroll
            for (int ks = 0; ks < 2; ks++) {
                f16x8 a  = *(const f16x8*)&reg1[ROW128(ra, hh * 64 + ks * 32 + gq * 8)];
                f16x8 bb = *(const f16x8*)&reg2[ROW128(rb, hh * 64 + ks * 32 + gq * 8)];
                acc = MFMA(a, bb, acc);
            }
            const bool cv = (l15 < 11);
            #pragma unroll
            for (int i = 0; i < 4; i++) {
                int p = gq * 4 + i;
                float v = cv ? acc[i] * 0.125f : -1e30f;
                float mx = v;
                #pragma unroll
                for (int off = 8; off; off >>= 1) mx = fmaxf(mx, __shfl_xor(mx, off));
                float e = cv ? __expf(v - mx) : 0.f;
                float s = e;
                #pragma unroll
                for (int off = 8; off; off >>= 1) s += __shfl_xor(s, off);
                float is = 1.f / s;
                att2e[hh * 512 + ATIDX(p, 2 * l15)]     = (f16_t)((p < 10) ? e * is : 0.f);
                att2e[hh * 512 + ATIDX(p, 2 * l15 + 1)] = (f16_t)0.f;
            }
        }
    }
    __syncthreads();

    // ---- P6: y = attb @ v; y2 = att2e @ v; prefetch P7a's wg/wr fragments ----
    f16x8 wgf_pre[2][4], wrf_pre[2][4];
    {
        f16_t* attb  = (f16_t*)pool;
        f16_t* att2e = (f16_t*)pool + 2048;
        f16_t* y2bb  = reg1;                          // [10][128] f16 swz
        for (int t = w * 6; t < w * 6 + 6; ++t) {     // 24 tiles: 16 y + 8 y2
            int hh, dloc, mt = 0, isY2;
            if (t < 16) { hh = t >> 3; mt = (t >> 2) & 1; dloc = hh * 64 + (t & 3) * 16 + l15; isY2 = 0; }
            else        { int u = t - 16; hh = u >> 2;    dloc = hh * 64 + (u & 3) * 16 + l15; isY2 = 1; }
            f16x8 a;
            if (!isY2) { int r = mt * 16 + l15; a = *(const f16x8*)&attb[hh * 1024 + ATIDX(r, gq * 8)]; }
            else       {                        a = *(const f16x8*)&att2e[hh * 512 + ATIDX(l15, gq * 8)]; }
            f16x8 bb = *(const f16x8*)&reg3[VTIDX(dloc, gq * 8)];
            f32x4 acc = {0.f, 0.f, 0.f, 0.f};
            acc = MFMA(a, bb, acc);
            if (!isY2) {
                #pragma unroll
                for (int i = 0; i < 4; i++) reg2[ROW128(mt * 16 + gq * 4 + i, dloc)] = (f16_t)acc[i];
            } else {
                #pragma unroll
                for (int i = 0; i < 4; i++) {
                    int rr2 = gq * 4 + i;
                    if (rr2 < 10) y2bb[ROW128(rr2, dloc)] = (f16_t)acc[i];
                }
            }
        }
        // prefetch P7a weights (independent of LDS, hides under next barrier+phase)
        #pragma unroll
        for (int q2 = 0; q2 < 2; q2++) {
            int n = (w * 2 + q2) * 16 + l15;
            #pragma unroll
            for (int ks = 0; ks < 4; ks++) {
                wgf_pre[q2][ks] = *(const f16x8*)&wgb[((ks * 4 + gq) * 128 + n) * 8];
                wrf_pre[q2][ks] = *(const f16x8*)&wrb[((ks * 4 + gq) * 128 + n) * 8];
            }
        }
    }
    __syncthreads();

    // ---- P7a: gate & refine GEMMs (prefetched weights); prefetch P7b's wo + x ----
    f16x8 wo_pre[4][4];
    float xv[4][4];
    {
        f16_t* y2bb = reg1;
        float mn = normv[10];
        float* gyb = (float*)reg3;                    // [10][128] f32
        #pragma unroll
        for (int q2 = 0; q2 < 2; q2++) {
            int nt = w * 2 + q2;
            int n = nt * 16 + l15;
            int yrow = l15 < 10 ? l15 : 0;
            int hr   = l15 < 10 ? 2 * l15 + 1 : 1;
            f32x4 accg = {0.f, 0.f, 0.f, 0.f}, accr = {0.f, 0.f, 0.f, 0.f};
            #pragma unroll
            for (int ks = 0; ks < 4; ks++) {
                f16x8 ha  = *(const f16x8*)&hsb[ROW128(hr, ks * 32 + gq * 8)];
                f16x8 ya  = *(const f16x8*)&y2bb[ROW128(yrow, ks * 32 + gq * 8)];
                accg = MFMA(ha, wgf_pre[q2][ks], accg);
                accr = MFMA(ya, wrf_pre[q2][ks], accr);
            }
            float bgc = bg[n], brc = br[n];
            #pragma unroll
            for (int i = 0; i < 4; i++) {
                int p = gq * 4 + i;
                if (p < 10) {
                    float gate = 1.f / (1.f + __expf(-(accg[i] + bgc)));
                    float u = 1.f - 1.f / (1.f + __expf(-(normv[p] - mn)));
                    gyb[p * 128 + n] = u * gate * (accr[i] + brc);
                }
            }
        }
        // prefetch P7b weights and x residuals
        #pragma unroll
        for (int t2 = 0; t2 < 4; t2++) {
            int t = w * 4 + t2;
            int mt = t >> 3, nt = t & 7;
            int n = nt * 16 + l15;
            #pragma unroll
            for (int ks = 0; ks < 4; ks++)
                wo_pre[t2][ks] = *(const f16x8*)&wo[((ks * 4 + gq) * 128 + n) * 8];
            #pragma unroll
            for (int i = 0; i < 4; i++) {
                int r = mt * 16 + gq * 4 + i;
                xv[t2][i] = (r < 21) ? xb[r * 128 + n] : 0.f;
            }
        }
    }
    __syncthreads();

    // ---- P7b: out = x + y @ Wout + bout (+ gy on patch rows) ----
    {
        float* gyb = (float*)reg3;
        float* ob = out + (size_t)b * 2688;
        #pragma unroll
        for (int t2 = 0; t2 < 4; t2++) {
            int t = w * 4 + t2;
            int mt = t >> 3, nt = t & 7;
            int n = nt * 16 + l15;
            f32x4 acc = {0.f, 0.f, 0.f, 0.f};
            #pragma unroll
            for (int ks = 0; ks < 4; ks++) {
                f16x8 a = *(const f16x8*)&reg2[ROW128(mt * 16 + l15, ks * 32 + gq * 8)];
                acc = MFMA(a, wo_pre[t2][ks], acc);
            }
            float bo = bout[n];
            #pragma unroll
            for (int i = 0; i < 4; i++) {
                int r = mt * 16 + gq * 4 + i;
                if (r < 21) {
                    float v = xv[t2][i] + acc[i] + bo;
                    if (r & 1) v += gyb[((r - 1) >> 1) * 128 + n];
                    ob[r * 128 + n] = v;
                }
            }
        }
    }
}

extern "C" void kernel_launch(void* const* d_in, const int* in_sizes, int n_in,
                              void* d_out, int out_size, void* d_ws, size_t ws_size,
                              hipStream_t stream)
{
    (void)in_sizes; (void)n_in; (void)out_size; (void)ws_size;
    const float* x    = (const float*)d_in[0];
    const float* fcr  = (const float*)d_in[1];
    const float* fci  = (const float*)d_in[2];
    const float* g    = (const float*)d_in[3];
    const float* Wqkv = (const float*)d_in[4];
    const float* bqkv = (const float*)d_in[5];
    const float* Wout = (const float*)d_in[6];
    const float* bout = (const float*)d_in[7];
    const float* Wg   = (const float*)d_in[8];
    const float* bg   = (const float*)d_in[9];
    const float* Wr   = (const float*)d_in[10];
    const float* br   = (const float*)d_in[11];
    const float* Bb   = (const float*)d_in[12];
    float* out = (float*)d_out;

    char* wsb = (char*)d_ws;
    float* part = (float*)wsb;                          // 64 slots x 16-float stride (4KB)
    f16_t* wq  = (f16_t*)(wsb + 4096);                  // 49152 f16
    f16_t* wo  = wq + 49152;                            // 16384
    f16_t* wgb = wo + 16384;                            // 16384
    f16_t* wrb = wgb + 16384;                           // 16384 ; ws use ~200 KB

    hipMemsetAsync(part, 0, 4096, stream);
    hipLaunchKernelGGL(k_prep, dim3(2944), dim3(256), 0, stream,
                       Wqkv, Wout, Wg, Wr, x, g, wq, wo, wgb, wrb, part);
    hipLaunchKernelGGL(k_main, dim3(NB),   dim3(256), 0, stream,
                       x, fcr, fci, g, bqkv, bout, bg, br, Bb, part, wq, wo, wgb, wrb, out);
}